// Round 1
// 189.706 us; speedup vs baseline: 1.0412x; 1.0412x over previous
//
#include <hip/hip_runtime.h>
#include <hip/hip_bf16.h>

typedef __attribute__((ext_vector_type(8))) short short8;
typedef __attribute__((ext_vector_type(4))) float floatx4;

static constexpr int Hh = 56, Wd = 56, HWsz = 3136;
static constexpr float EPS = 1e-5f;

__device__ __forceinline__ unsigned short f2bf(float f) {
    __hip_bfloat16 h = __float2bfloat16(f);
    return *reinterpret_cast<unsigned short*>(&h);
}
__device__ __forceinline__ unsigned pack2(float a, float b) {
    return (unsigned)f2bf(a) | ((unsigned)f2bf(b) << 16);
}
__device__ __forceinline__ short8 as_short8(uint4 v) {
    union { uint4 u; short8 s; } c; c.u = v; return c.s;
}

// ---------------------------------------------------------------------------
// prep: pack weights into MFMA A-fragment order (bf16) + fold BN affines.
// ---------------------------------------------------------------------------
__global__ __launch_bounds__(256) void prep(
    const float* __restrict__ w1, const float* __restrict__ w3,
    const float* __restrict__ c1w,
    const float* __restrict__ bn1g, const float* __restrict__ bn1b,
    const float* __restrict__ bn1m, const float* __restrict__ bn1v,
    const float* __restrict__ ibg, const float* __restrict__ ibb,
    const float* __restrict__ ibm, const float* __restrict__ ibv,
    const float* __restrict__ bn2g, const float* __restrict__ bn2b,
    const float* __restrict__ bn2m, const float* __restrict__ bn2v,
    const float* __restrict__ bn3g, const float* __restrict__ bn3b,
    const float* __restrict__ bn3m, const float* __restrict__ bn3v,
    unsigned short* __restrict__ w1p, unsigned short* __restrict__ w3p,
    unsigned short* __restrict__ c1wp,
    float* __restrict__ bn1s, float* __restrict__ bn1o,
    float* __restrict__ ibs,  float* __restrict__ ibo,
    float* __restrict__ bn2s, float* __restrict__ bn2o,
    float* __restrict__ bn3s, float* __restrict__ bn3o)
{
    const int idx = blockIdx.x * 256 + threadIdx.x;   // grid 64 -> 16384
    {
        const int j = idx & 7, ln = (idx >> 3) & 63, ks = (idx >> 9) & 7, mb = idx >> 12;
        const int m = mb * 16 + (ln & 15), k = ks * 32 + ((ln >> 4) & 3) * 8 + j;
        w1p[idx] = f2bf(w1[m * 256 + k]);
    }
    {
        const int j = idx & 7, ln = (idx >> 3) & 63, ks = (idx >> 9) & 1, mb = idx >> 10;
        const int m = mb * 16 + (ln & 15), k = ks * 32 + ((ln >> 4) & 3) * 8 + j;
        w3p[idx] = f2bf(w3[m * 64 + k]);
    }
    if (idx < 1024) {
        const int j = idx & 7, ln = (idx >> 3) & 63, ks = idx >> 9;
        const int m = ln & 15, k = ks * 32 + ((ln >> 4) & 3) * 8 + j;
        c1wp[idx] = f2bf(c1w[m * 64 + k]);
    }
    if (idx < 64)  { float s = bn1g[idx] * rsqrtf(bn1v[idx] + EPS); bn1s[idx] = s; bn1o[idx] = bn1b[idx] - bn1m[idx] * s; }
    if (idx < 16)  { float s = ibg[idx]  * rsqrtf(ibv[idx]  + EPS); ibs[idx]  = s; ibo[idx]  = ibb[idx]  - ibm[idx]  * s; }
    if (idx < 64)  { float s = bn2g[idx] * rsqrtf(bn2v[idx] + EPS); bn2s[idx] = s; bn2o[idx] = bn2b[idx] - bn2m[idx] * s; }
    if (idx < 256) { float s = bn3g[idx] * rsqrtf(bn3v[idx] + EPS); bn3s[idx] = s; bn3o[idx] = bn3b[idx] - bn3m[idx] * s; }
}

// ---------------------------------------------------------------------------
// K1: conv1 via MFMA (M=64 ch, K=256, N=64 px/block) + BN1 + ReLU.
// x staged via float4 loads along px (16 VMEM/thread vs 64 scalar).
// out1c layout: [b][ch>>3][hw][8] fp32 (channel-last chunks) -> dense float4
// stores here, dense float4 halo loads in k2.
// tbufp layout: [b][hw][16] fp32 -> one float4 store per lane here,
// 4 float4 loads per thread in k2.
// ---------------------------------------------------------------------------
__global__ __launch_bounds__(256) void k1_conv1_branch(
    const float* __restrict__ x, const unsigned short* __restrict__ w1p,
    const float* __restrict__ bn1s, const float* __restrict__ bn1o,
    const unsigned short* __restrict__ c1wp,
    const float* __restrict__ ibs, const float* __restrict__ ibo,
    float* __restrict__ out1c, float* __restrict__ tbufp)
{
    __shared__ unsigned short xls[64 * 264];   // 33 KB: [px][c] bf16, stride 264
    __shared__ unsigned short tls[64 * 72];    // 9 KB:  [px][ch] bf16, stride 72
    const int tid  = threadIdx.x;
    const int lane = tid & 63;
    const int n    = lane & 15;
    const int quad = lane >> 4;
    const int wv   = tid >> 6;
    const int pix0 = blockIdx.x * 64;
    const int b    = pix0 / HWsz;
    const int hw0  = pix0 - b * HWsz;

    // stage x: thread (cp0 = tid&15, px4 = (tid>>4)&15) loads channel-pairs
    // cp0+16i as float4 along px (rows 4*px4..4*px4+3). Global: 1KB/instr.
    // LDS b32 transpose-writes: banks = cp0 + {0,16} + const -> 2-way (free).
    {
        const int cp0 = tid & 15;
        const int px4 = (tid >> 4) & 15;
        const float* xb = x + (size_t)b * 256 * HWsz + hw0 + px4 * 4;
        unsigned short* dst = xls + (px4 * 4) * 264 + 2 * cp0;
#pragma unroll
        for (int i = 0; i < 8; ++i) {
            const float4 v0 = *reinterpret_cast<const float4*>(xb + (size_t)(32 * i + 2 * cp0) * HWsz);
            const float4 v1 = *reinterpret_cast<const float4*>(xb + (size_t)(32 * i + 2 * cp0 + 1) * HWsz);
            unsigned short* d = dst + 32 * i;
            *reinterpret_cast<unsigned*>(d)           = pack2(v0.x, v1.x);
            *reinterpret_cast<unsigned*>(d + 264)     = pack2(v0.y, v1.y);
            *reinterpret_cast<unsigned*>(d + 2 * 264) = pack2(v0.z, v1.z);
            *reinterpret_cast<unsigned*>(d + 3 * 264) = pack2(v0.w, v1.w);
        }
    }

    // A fragments (this wave's 16 output channels, full K=256)
    short8 afr[8];
    {
        const uint4* wp = reinterpret_cast<const uint4*>(w1p);
#pragma unroll
        for (int ks = 0; ks < 8; ++ks)
            afr[ks] = as_short8(wp[(wv * 8 + ks) * 64 + lane]);
    }
    __syncthreads();

    const floatx4 zero = {0.f, 0.f, 0.f, 0.f};
    floatx4 acc[4];
#pragma unroll
    for (int nt = 0; nt < 4; ++nt) acc[nt] = zero;

#pragma unroll
    for (int nt = 0; nt < 4; ++nt) {
        const unsigned short* bp = xls + (nt * 16 + n) * 264 + quad * 8;
#pragma unroll
        for (int ks = 0; ks < 8; ++ks) {
            const short8 bfr = *reinterpret_cast<const short8*>(bp + ks * 32);
            acc[nt] = __builtin_amdgcn_mfma_f32_16x16x32_bf16(afr[ks], bfr, acc[nt], 0, 0, 0);
        }
    }

    // epilogue: BN1 + ReLU; out1c fp32 [b][c8][px][8] via float4; tile -> tls
    const int och = wv * 16 + quad * 4;
    float sr[4], og[4];
#pragma unroll
    for (int r = 0; r < 4; ++r) { sr[r] = bn1s[och + r]; og[r] = bn1o[och + r]; }
    float* obase = out1c + ((size_t)b * 8 + (och >> 3)) * (HWsz * 8) + (och & 7);
#pragma unroll
    for (int nt = 0; nt < 4; ++nt) {
        float f[4];
#pragma unroll
        for (int r = 0; r < 4; ++r)
            f[r] = fmaxf(fmaf(acc[nt][r], sr[r], og[r]), 0.f);
        const int px = nt * 16 + n;
        float4 fv; fv.x = f[0]; fv.y = f[1]; fv.z = f[2]; fv.w = f[3];
        *reinterpret_cast<float4*>(obase + (size_t)(hw0 + px) * 8) = fv;
        uint2 pk;
        pk.x = pack2(f[0], f[1]);
        pk.y = pack2(f[2], f[3]);
        *reinterpret_cast<uint2*>(tls + px * 72 + och) = pk;
    }
    __syncthreads();

    // branch: t = relu(bn(c1w @ out1_tile)); wave wv does px-subtile wv
    floatx4 tacc = zero;
    {
        const uint4* cp4 = reinterpret_cast<const uint4*>(c1wp);
        const unsigned short* bp = tls + (wv * 16 + n) * 72 + quad * 8;
#pragma unroll
        for (int ks = 0; ks < 2; ++ks) {
            const short8 af = as_short8(cp4[ks * 64 + lane]);
            const short8 bf = *reinterpret_cast<const short8*>(bp + ks * 32);
            tacc = __builtin_amdgcn_mfma_f32_16x16x32_bf16(af, bf, tacc, 0, 0, 0);
        }
    }
    {
        const int g0 = quad * 4;
        float4 t4;
        t4.x = fmaxf(fmaf(tacc[0], ibs[g0 + 0], ibo[g0 + 0]), 0.f);
        t4.y = fmaxf(fmaf(tacc[1], ibs[g0 + 1], ibo[g0 + 1]), 0.f);
        t4.z = fmaxf(fmaf(tacc[2], ibs[g0 + 2], ibo[g0 + 2]), 0.f);
        t4.w = fmaxf(fmaf(tacc[3], ibs[g0 + 3], ibo[g0 + 3]), 0.f);
        *reinterpret_cast<float4*>(tbufp + ((size_t)b * HWsz + hw0 + wv * 16 + n) * 16 + g0) = t4;
    }
}

// ---------------------------------------------------------------------------
// K2: involution + BN2 + ReLU. grid (7, 64 bg, 2 halves), 448 thr, 1 px/thr.
// Halo staged from channel-last out1c via 2x float4 per pixel + ds_write_b128;
// tv via 4x float4 from [b][hw][16] tbufp.
// ---------------------------------------------------------------------------
__global__ __launch_bounds__(448) void k2_involution(
    const float* __restrict__ out1c, const float* __restrict__ tbufp,
    const float* __restrict__ c2w, const float* __restrict__ c2b,
    const float* __restrict__ bn2s, const float* __restrict__ bn2o,
    unsigned short* __restrict__ out2b)
{
    __shared__ float lds[14 * 62 * 12];   // 41.7 KB, pixel stride 12 floats
    const int r0  = blockIdx.x * 8;
    const int b   = blockIdx.y >> 2, g = blockIdx.y & 3;
    const int ch0 = g * 16 + blockIdx.z * 8;
    const int tid = threadIdx.x;
    const int row = tid / 56;
    const int col = tid - row * 56;
    const int hw  = (r0 + row) * Wd + col;

    // halo staging: [rr][cc][c] fp32; source is channel-last -> float4 pair
    const float* src = out1c + ((size_t)b * 8 + (ch0 >> 3)) * (HWsz * 8);
    for (int idx = tid; idx < 14 * 62; idx += 448) {
        const int rr = idx / 62, cc = idx - rr * 62;
        const int gr = r0 + rr - 3, gc = cc - 3;
        const bool in = (gr >= 0) & (gr < Hh) & (gc >= 0) & (gc < Wd);
        float4 a0 = {0.f, 0.f, 0.f, 0.f}, a1 = {0.f, 0.f, 0.f, 0.f};
        if (in) {
            const float* s = src + (size_t)(gr * Wd + gc) * 8;
            a0 = *reinterpret_cast<const float4*>(s);
            a1 = *reinterpret_cast<const float4*>(s + 4);
        }
        float* d = &lds[idx * 12];
        *reinterpret_cast<float4*>(d)     = a0;
        *reinterpret_cast<float4*>(d + 4) = a1;
    }

    // per-pixel t (4x float4), then all 49 weights (pure VALU + s_load)
    float tv[16];
    {
        const float* tp = tbufp + ((size_t)b * HWsz + hw) * 16;
#pragma unroll
        for (int q4 = 0; q4 < 4; ++q4)
            *reinterpret_cast<float4*>(tv + q4 * 4) = *reinterpret_cast<const float4*>(tp + q4 * 4);
    }
    float wk[49];
    {
        const float* cwb = c2w + g * 49 * 16;
        const float* cbb = c2b + g * 49;
#pragma unroll
        for (int j = 0; j < 49; ++j) {
            float a = cbb[j];
#pragma unroll
            for (int q = 0; q < 16; ++q)
                a = fmaf(cwb[j * 16 + q], tv[q], a);
            wk[j] = a;
        }
    }
    __syncthreads();

    float acc[8];
#pragma unroll
    for (int i = 0; i < 8; ++i) acc[i] = 0.f;

#pragma unroll
    for (int kh = 0; kh < 7; ++kh) {
#pragma unroll
        for (int kw = 0; kw < 7; ++kw) {
            const float* p = &lds[((row + kh) * 62 + (col + kw)) * 12];
            const float4 a0 = *reinterpret_cast<const float4*>(p);
            const float4 a1 = *reinterpret_cast<const float4*>(p + 4);
            const float w = wk[kh * 7 + kw];
            acc[0] = fmaf(w, a0.x, acc[0]);
            acc[1] = fmaf(w, a0.y, acc[1]);
            acc[2] = fmaf(w, a0.z, acc[2]);
            acc[3] = fmaf(w, a0.w, acc[3]);
            acc[4] = fmaf(w, a1.x, acc[4]);
            acc[5] = fmaf(w, a1.y, acc[5]);
            acc[6] = fmaf(w, a1.z, acc[6]);
            acc[7] = fmaf(w, a1.w, acc[7]);
        }
    }

    float f[8];
#pragma unroll
    for (int i = 0; i < 8; ++i)
        f[i] = fmaxf(fmaf(acc[i], bn2s[ch0 + i], bn2o[ch0 + i]), 0.f);
    uint4 pk;
    pk.x = pack2(f[0], f[1]); pk.y = pack2(f[2], f[3]);
    pk.z = pack2(f[4], f[5]); pk.w = pack2(f[6], f[7]);
    *reinterpret_cast<uint4*>(out2b + ((size_t)b * HWsz + hw) * 64 + ch0) = pk;
}

// ---------------------------------------------------------------------------
// K3: conv3 via MFMA (M=256, K=64, N=64 px/block) + BN3 + residual + ReLU.
// Epilogue transposes each 16x16 tile through per-wave LDS (wave-local, no
// __syncthreads) so residual loads + stores are float4 (16 lines x 64B/instr)
// instead of 128 scalar strided VMEM ops.
// ---------------------------------------------------------------------------
__global__ __launch_bounds__(256) void k3_conv3(
    const unsigned short* __restrict__ out2b, const float* __restrict__ x,
    const unsigned short* __restrict__ w3p,
    const float* __restrict__ bn3s, const float* __restrict__ bn3o,
    float* __restrict__ out)
{
    __shared__ unsigned short bls[64 * 72];   // 9 KB bf16 [px][ch]
    __shared__ float bnl[512];                // (s,o) pairs for 256 outs
    __shared__ float ldst[4 * 2 * 16 * 20];   // 10 KB per-wave dbuf transpose
    const int tid  = threadIdx.x;
    const int lane = tid & 63;
    const int n    = lane & 15;
    const int quad = lane >> 4;
    const int wv   = tid >> 6;
    const int pix0 = blockIdx.x * 64;
    const int b    = pix0 / HWsz;
    const int hw0  = pix0 - b * HWsz;

    // stage out2b tile: thread (px=tid&63, ck=tid>>6) loads chunks ck, ck+4
    {
        const int px = tid & 63;
        const int ck = tid >> 6;
        const unsigned short* ob = out2b + ((size_t)b * HWsz + hw0 + px) * 64;
        const uint4 v0 = *reinterpret_cast<const uint4*>(ob + ck * 8);
        const uint4 v1 = *reinterpret_cast<const uint4*>(ob + (ck + 4) * 8);
        *reinterpret_cast<uint4*>(bls + px * 72 + ck * 8)       = v0;
        *reinterpret_cast<uint4*>(bls + px * 72 + (ck + 4) * 8) = v1;
        bnl[tid * 2]     = bn3s[tid];
        bnl[tid * 2 + 1] = bn3o[tid];
    }
    __syncthreads();

    short8 bf[2];
#pragma unroll
    for (int ks = 0; ks < 2; ++ks)
        bf[ks] = *reinterpret_cast<const short8*>(bls + (wv * 16 + n) * 72 + ks * 32 + quad * 8);

    const floatx4 zero = {0.f, 0.f, 0.f, 0.f};
    floatx4 acc[16];
#pragma unroll
    for (int mb = 0; mb < 16; ++mb) acc[mb] = zero;

    const uint4* wp = reinterpret_cast<const uint4*>(w3p);
#pragma unroll
    for (int mb = 0; mb < 16; ++mb) {
        const short8 a0 = as_short8(wp[(mb * 2 + 0) * 64 + lane]);
        const short8 a1 = as_short8(wp[(mb * 2 + 1) * 64 + lane]);
        acc[mb] = __builtin_amdgcn_mfma_f32_16x16x32_bf16(a0, bf[0], acc[mb], 0, 0, 0);
        acc[mb] = __builtin_amdgcn_mfma_f32_16x16x32_bf16(a1, bf[1], acc[mb], 0, 0, 0);
    }

    // epilogue: BN3 (pre-transpose) -> wave-local LDS transpose -> residual +
    // ReLU with float4 x loads / out stores.
    const int colg0 = hw0 + wv * 16;
    float* lt0 = ldst + wv * (2 * 16 * 20);
#pragma unroll
    for (int mb = 0; mb < 16; ++mb) {
        float* lt = lt0 + (mb & 1) * (16 * 20);
#pragma unroll
        for (int r = 0; r < 4; ++r) {
            const int o = mb * 16 + quad * 4 + r;
            const float2 so = *reinterpret_cast<const float2*>(&bnl[o * 2]);
            lt[(quad * 4 + r) * 20 + n] = fmaf(acc[mb][r], so.x, so.y);
        }
        // wave-internal RAW through LDS: compiler orders via lgkmcnt
        const float4 t4 = *reinterpret_cast<const float4*>(lt + n * 20 + quad * 4);
        const size_t gi = ((size_t)b * 256 + mb * 16 + n) * HWsz + colg0 + quad * 4;
        const float4 xr = *reinterpret_cast<const float4*>(x + gi);
        float4 ov;
        ov.x = fmaxf(t4.x + xr.x, 0.f);
        ov.y = fmaxf(t4.y + xr.y, 0.f);
        ov.z = fmaxf(t4.z + xr.z, 0.f);
        ov.w = fmaxf(t4.w + xr.w, 0.f);
        *reinterpret_cast<float4*>(out + gi) = ov;
    }
}

extern "C" void kernel_launch(void* const* d_in, const int* in_sizes, int n_in,
                              void* d_out, int out_size, void* d_ws, size_t ws_size,
                              hipStream_t stream)
{
    const float* x    = (const float*)d_in[0];
    const float* w1   = (const float*)d_in[1];
    const float* bn1g = (const float*)d_in[2];
    const float* bn1b = (const float*)d_in[3];
    const float* bn1m = (const float*)d_in[4];
    const float* bn1v = (const float*)d_in[5];
    const float* c1w  = (const float*)d_in[6];
    const float* ibg  = (const float*)d_in[7];
    const float* ibb  = (const float*)d_in[8];
    const float* ibm  = (const float*)d_in[9];
    const float* ibv  = (const float*)d_in[10];
    const float* c2w  = (const float*)d_in[11];
    const float* c2b  = (const float*)d_in[12];
    const float* bn2g = (const float*)d_in[13];
    const float* bn2b = (const float*)d_in[14];
    const float* bn2m = (const float*)d_in[15];
    const float* bn2v = (const float*)d_in[16];
    const float* w3   = (const float*)d_in[17];
    const float* bn3g = (const float*)d_in[18];
    const float* bn3b = (const float*)d_in[19];
    const float* bn3m = (const float*)d_in[20];
    const float* bn3v = (const float*)d_in[21];

    // ws layout (float units)
    float* wsf = (float*)d_ws;
    float*          out1c = wsf;                                  // 3211264
    unsigned short* out2b = (unsigned short*)(wsf + 3211264);     // 3211264 us
    float*          tbufp = wsf + 4816896;                        // 802816
    unsigned short* w1p   = (unsigned short*)(wsf + 5619712);     // 16384 us
    unsigned short* w3p   = (unsigned short*)(wsf + 5627904);     // 16384 us
    unsigned short* c1wp  = (unsigned short*)(wsf + 5636096);     // 1024 us
    float* bn1s = wsf + 5636608; float* bn1o = wsf + 5636672;
    float* ibs  = wsf + 5636736; float* ibo  = wsf + 5636752;
    float* bn2s = wsf + 5636768; float* bn2o = wsf + 5636832;
    float* bn3s = wsf + 5636896; float* bn3o = wsf + 5637152;

    prep<<<dim3(64), dim3(256), 0, stream>>>(
        w1, w3, c1w, bn1g, bn1b, bn1m, bn1v, ibg, ibb, ibm, ibv,
        bn2g, bn2b, bn2m, bn2v, bn3g, bn3b, bn3m, bn3v,
        w1p, w3p, c1wp, bn1s, bn1o, ibs, ibo, bn2s, bn2o, bn3s, bn3o);

    k1_conv1_branch<<<dim3(784), dim3(256), 0, stream>>>(
        x, w1p, bn1s, bn1o, c1wp, ibs, ibo, out1c, tbufp);

    k2_involution<<<dim3(7, 64, 2), dim3(448), 0, stream>>>(
        out1c, tbufp, c2w, c2b, bn2s, bn2o, out2b);

    k3_conv3<<<dim3(784), dim3(256), 0, stream>>>(
        out2b, x, w3p, bn3s, bn3o, (float*)d_out);
}